// Round 8
// baseline (239.764 us; speedup 1.0000x reference)
//
#include <hip/hip_runtime.h>
#include <hip/hip_bf16.h>

// Problem constants (CausalSelfAttention_23768349016530)
#define B_  8
#define N_  1024
#define C_  768
#define H_  12
#define D_  64
#define C3  2304   // 3*C
#define C2  1536   // 2*C

typedef unsigned short ushort_t;
typedef __attribute__((ext_vector_type(8))) short bf16x8;   // 8 bf16 = 4 VGPR
typedef __attribute__((ext_vector_type(4))) short bf16x4;   // 4 bf16 = 2 VGPR
typedef __attribute__((ext_vector_type(4))) float f32x4;    // MFMA 16x16 accumulator

#if __has_builtin(__builtin_amdgcn_mfma_f32_16x16x16_bf16)
#define MFMA16(A, B, C) __builtin_amdgcn_mfma_f32_16x16x16_bf16(A, B, C, 0, 0, 0)
#else
#define MFMA16(A, B, C) __builtin_amdgcn_mfma_f32_16x16x16bf16_1k(A, B, C, 0, 0, 0)
#endif

// exp2: native v_exp_f32
__device__ __forceinline__ float fast_exp2(float x) {
#if __has_builtin(__builtin_amdgcn_exp2f)
    return __builtin_amdgcn_exp2f(x);
#else
    return exp2f(x);
#endif
}

__device__ __forceinline__ float bf2f(ushort_t u) {
    union { unsigned int i; float f; } v;
    v.i = ((unsigned int)u) << 16;
    return v.f;
}

__device__ __forceinline__ ushort_t f2bf(float f) {
    union { float f; unsigned int i; } v;
    v.f = f;
    unsigned int x = v.i;
    if ((x & 0x7f800000u) == 0x7f800000u && (x & 0x007fffffu))
        return (ushort_t)((x >> 16) | 0x0040u);   // quiet NaN
    return (ushort_t)((x + 0x7fffu + ((x >> 16) & 1u)) >> 16);  // RNE
}

__device__ __forceinline__ void st1(float* p, float v) { *p = v; }
__device__ __forceinline__ void st1(ushort_t* p, float v) { *p = f2bf(v); }

// ---------------------------------------------------------------------------
// fp32 -> bf16 elementwise (for x)
// ---------------------------------------------------------------------------
__global__ __launch_bounds__(256) void cvt_bf16(
    const float* __restrict__ X, ushort_t* __restrict__ Y, int n)
{
    int i = (blockIdx.x * 256 + threadIdx.x) * 4;
    if (i < n) {
        float4 f = *reinterpret_cast<const float4*>(X + i);
        ushort4 o;
        o.x = f2bf(f.x); o.y = f2bf(f.y); o.z = f2bf(f.z); o.w = f2bf(f.w);
        *reinterpret_cast<ushort4*>(Y + i) = o;
    }
}

// ---------------------------------------------------------------------------
// W[K][Nn] fp32  ->  WT[Nn][K] bf16   (32x32 LDS tile transpose)
// ---------------------------------------------------------------------------
__global__ __launch_bounds__(256) void transpose_to_bf16(
    const float* __restrict__ W, ushort_t* __restrict__ WT, int K, int Nn)
{
    __shared__ float t[32][33];
    const int n0 = blockIdx.x * 32, k0 = blockIdx.y * 32;
    const int tx = threadIdx.x & 31, ty = threadIdx.x >> 5;   // ty: 0..7
    #pragma unroll
    for (int i = 0; i < 4; ++i) {
        const int k = ty + i * 8;
        t[k][tx] = W[(size_t)(k0 + k) * Nn + n0 + tx];
    }
    __syncthreads();
    #pragma unroll
    for (int i = 0; i < 4; ++i) {
        const int n = ty + i * 8;
        WT[(size_t)(n0 + n) * K + k0 + tx] = f2bf(t[tx][n]);
    }
}

// ---------------------------------------------------------------------------
// MFMA GEMM: 128x128 tile, BK=64, 256 thr, XOR-swizzled LDS.
// SCALEQ: multiply (acc+bias) by 0.125*log2(e) for Q columns (< C_), folding
// both the softmax scale and the exp->exp2 conversion into Q.
// vtOut!=null && col0>=2C: write V transposed to vt[b][h][d][n].
// ---------------------------------------------------------------------------
#define GBK 64
#define QSCALE 0.18033688011112042f   // 0.125 * log2(e)

__device__ __forceinline__ void gld_lds16(const ushort_t* g, ushort_t* lds) {
    __builtin_amdgcn_global_load_lds(
        (const __attribute__((address_space(1))) void*)g,
        (__attribute__((address_space(3))) void*)lds, 16, 0, 0);
}

template<typename TO, bool SCALEQ>
__global__ __launch_bounds__(256) void gemm_mfma(
    const ushort_t* __restrict__ A, const ushort_t* __restrict__ BT,
    const float* __restrict__ bias, TO* __restrict__ Y, int ldY,
    ushort_t* __restrict__ vtOut, int M, int K, int Nn)
{
    __shared__ ushort_t As[128 * GBK];   // [row][slot^], 128B rows
    __shared__ ushort_t Bs[128 * GBK];

    const int tid  = threadIdx.x;
    const int wave = tid >> 6;
    const int lane = tid & 63;
    const int row0 = blockIdx.y * 128;
    const int col0 = blockIdx.x * 128;
    const int wr   = (wave >> 1) * 64;
    const int wc   = (wave & 1) * 64;
    const int l15  = lane & 15;
    const int quad = lane >> 4;
    const int l7   = l15 & 7;

    const int srow = lane >> 3;                 // 0..7
    const int sg   = (lane & 7) ^ srow;         // data granule to fetch

    f32x4 acc[4][4] = {};

    for (int k0 = 0; k0 < K; k0 += GBK) {
        __syncthreads();
        #pragma unroll
        for (int it = 0; it < 4; ++it) {
            const int baseRow = wave * 32 + it * 8;           // wave-uniform
            const int r = baseRow + srow;
            gld_lds16(&A [(size_t)(row0 + r) * K + k0 + sg * 8], &As[baseRow * GBK]);
            gld_lds16(&BT[(size_t)(col0 + r) * K + k0 + sg * 8], &Bs[baseRow * GBK]);
        }
        __syncthreads();

        #pragma unroll
        for (int kc = 0; kc < 2; ++kc) {
            bf16x8 af[4], bf[4];
            #pragma unroll
            for (int i = 0; i < 4; ++i) {
                const int aslot = (kc * 4 + quad) ^ l7;
                af[i] = *reinterpret_cast<const bf16x8*>(
                    &As[(wr + i * 16 + l15) * GBK + aslot * 8]);
                bf[i] = *reinterpret_cast<const bf16x8*>(
                    &Bs[(wc + i * 16 + l15) * GBK + aslot * 8]);
            }
            #pragma unroll
            for (int i = 0; i < 4; ++i)
                #pragma unroll
                for (int j = 0; j < 4; ++j)
                    acc[i][j] = __builtin_amdgcn_mfma_f32_16x16x32_bf16(
                        af[i], bf[j], acc[i][j], 0, 0, 0);
        }
    }

    const float qs = (SCALEQ && (col0 + wc) < C_) ? QSCALE : 1.0f;

    if (vtOut != nullptr && col0 >= C2) {
        // V part: write transposed vt[b][h][d][token]
        #pragma unroll
        for (int i = 0; i < 4; ++i) {
            const int r0 = row0 + wr + i * 16 + quad * 4;   // token base
            const int bb = r0 >> 10;
            const int n  = r0 & 1023;
            #pragma unroll
            for (int j = 0; j < 4; ++j) {
                const int c  = col0 + wc + j * 16 + l15;
                const int cv = c - C2;
                const int hh = cv >> 6, d = cv & 63;
                const float bv = bias[c];
                ushort4 o;
                o.x = f2bf(acc[i][j][0] + bv);
                o.y = f2bf(acc[i][j][1] + bv);
                o.z = f2bf(acc[i][j][2] + bv);
                o.w = f2bf(acc[i][j][3] + bv);
                *reinterpret_cast<ushort4*>(
                    &vtOut[((size_t)(bb * H_ + hh) * D_ + d) * N_ + n]) = o;
            }
        }
    } else {
        #pragma unroll
        for (int i = 0; i < 4; ++i) {
            const int r = row0 + wr + i * 16 + quad * 4;
            #pragma unroll
            for (int j = 0; j < 4; ++j) {
                const int c = col0 + wc + j * 16 + l15;
                const float bv = bias[c];
                #pragma unroll
                for (int t = 0; t < 4; ++t)
                    st1(&Y[(size_t)(r + t) * ldY + c], (acc[i][j][t] + bv) * qs);
            }
        }
    }
}

// ---------------------------------------------------------------------------
// MFMA attention, S^T formulation. Q pre-scaled by 0.125*log2e (gemm1).
// S^T = K·Q^T via 16x16x32 (C-layout: key=quad*4+t, q=l15). p=exp2(s) packed
// in-register to bf16 pairs -> used DIRECTLY as B-operand of 16x16x16 PV
// MFMA (B-layout == C-layout for K=16): O^T = V^T · P. No P LDS round-trip.
// K/V tiles double-buffered (register-staged), one barrier per tile.
// Pad mask applied at epilogue (masked row -> NaN, matching jax 0/0).
// ---------------------------------------------------------------------------
#define LDT 72

__global__ __launch_bounds__(256) void attn_mfma(
    const ushort_t* __restrict__ qk, const ushort_t* __restrict__ vt,
    const int* __restrict__ pad_mask, ushort_t* __restrict__ y)
{
    __shared__ ushort_t Ks [2][64 * LDT];   // K tile  [key][d]
    __shared__ ushort_t Vts[2][64 * LDT];   // V^T tile [d][key]

    const int tid  = threadIdx.x;
    const int wave = tid >> 6;
    const int lane = tid & 63;
    const int l15  = lane & 15;
    const int quad = lane >> 4;

    const int qt = blockIdx.x & 7;                // 8 q-tiles of 128
    const int h  = (blockIdx.x >> 3) % H_;
    const int b  = blockIdx.x / (8 * H_);
    const int q0 = qt * 128 + wave * 32;          // wave's first query row

    const ushort_t* qkB = qk + (size_t)b * N_ * C2;
    const ushort_t* vtB = vt + ((size_t)(b * H_ + h)) * D_ * N_;
    const int ho = h * D_;

    // Q as B-operand fragments: [n=q=l15][k=d=kc*32+quad*8+j]
    bf16x8 qf[2][2];
    #pragma unroll
    for (int rt = 0; rt < 2; ++rt)
        #pragma unroll
        for (int kc = 0; kc < 2; ++kc)
            qf[rt][kc] = *reinterpret_cast<const bf16x8*>(
                &qkB[(size_t)(q0 + rt * 16 + l15) * C2 + ho + kc * 32 + quad * 8]);

    // pad mask per q = rt*16 + l15 (epilogue only)
    int mrow[2];
    #pragma unroll
    for (int rt = 0; rt < 2; ++rt)
        mrow[rt] = pad_mask[b * N_ + q0 + rt * 16 + l15];

    f32x4 oacc[2][4] = {};   // [rt(q)][dt(d)] ; O^T: d=quad*4+t, q=l15
    float den[2] = {};

    const int srow = tid >> 3;          // staging: 0..31
    const int scol = (tid & 7) * 8;     // 16B granule within 64-elem row

    uint4 kr[2], vr[2];
    // prologue: tile 0 -> regs -> buf 0
    #pragma unroll
    for (int half = 0; half < 2; ++half) {
        const int r = srow + half * 32;
        kr[half] = *reinterpret_cast<const uint4*>(&qkB[(size_t)r * C2 + C_ + ho + scol]);
        vr[half] = *reinterpret_cast<const uint4*>(&vtB[(size_t)r * N_ + scol]);
    }
    #pragma unroll
    for (int half = 0; half < 2; ++half) {
        const int r = srow + half * 32;
        *reinterpret_cast<uint4*>(&Ks [0][r * LDT + scol]) = kr[half];
        *reinterpret_cast<uint4*>(&Vts[0][r * LDT + scol]) = vr[half];
    }

    for (int kt = 0; kt < 16; ++kt) {
        const int cur = kt & 1;
        if (kt < 15) {   // prefetch next tile into registers (latency hidden)
            const int k0 = (kt + 1) * 64;
            #pragma unroll
            for (int half = 0; half < 2; ++half) {
                const int r = srow + half * 32;
                kr[half] = *reinterpret_cast<const uint4*>(
                    &qkB[(size_t)(k0 + r) * C2 + C_ + ho + scol]);
                vr[half] = *reinterpret_cast<const uint4*>(
                    &vtB[(size_t)r * N_ + k0 + scol]);
            }
        }
        __syncthreads();   // buf[cur] writes visible; prev compute done

        // S^T = K Q^T : A=kf (m=key), B=qf (n=q)
        f32x4 s[2][4] = {};   // [rt(q)][ct(key tile)]
        #pragma unroll
        for (int kc = 0; kc < 2; ++kc) {
            bf16x8 kf[4];
            #pragma unroll
            for (int ct = 0; ct < 4; ++ct)
                kf[ct] = *reinterpret_cast<const bf16x8*>(
                    &Ks[cur][(ct * 16 + l15) * LDT + kc * 32 + quad * 8]);
            #pragma unroll
            for (int rt = 0; rt < 2; ++rt)
                #pragma unroll
                for (int ct = 0; ct < 4; ++ct)
                    s[rt][ct] = __builtin_amdgcn_mfma_f32_16x16x32_bf16(
                        kf[ct], qf[rt][kc], s[rt][ct], 0, 0, 0);
        }

        // p = exp2(s); den += p; pack pairs to bf16 (B-operand ready)
        bf16x4 pb[2][4];
        #pragma unroll
        for (int rt = 0; rt < 2; ++rt)
            #pragma unroll
            for (int ct = 0; ct < 4; ++ct) {
                float p0 = fast_exp2(s[rt][ct][0]);
                float p1 = fast_exp2(s[rt][ct][1]);
                float p2 = fast_exp2(s[rt][ct][2]);
                float p3 = fast_exp2(s[rt][ct][3]);
                den[rt] += (p0 + p1) + (p2 + p3);
                union { unsigned u[2]; bf16x4 v; } pk;
                pk.u[0] = ((__float_as_uint(p0) + 0x8000u) >> 16)
                        | ((__float_as_uint(p1) + 0x8000u) & 0xffff0000u);
                pk.u[1] = ((__float_as_uint(p2) + 0x8000u) >> 16)
                        | ((__float_as_uint(p3) + 0x8000u) & 0xffff0000u);
                pb[rt][ct] = pk.v;
            }

        // O^T += V^T P : A = V^T frag [m=d=l15][k=key=quad*4+i], B = pb
        #pragma unroll
        for (int kk = 0; kk < 4; ++kk) {
            bf16x4 va[4];
            #pragma unroll
            for (int dt = 0; dt < 4; ++dt)
                va[dt] = *reinterpret_cast<const bf16x4*>(
                    &Vts[cur][(dt * 16 + l15) * LDT + kk * 16 + quad * 4]);
            #pragma unroll
            for (int rt = 0; rt < 2; ++rt)
                #pragma unroll
                for (int dt = 0; dt < 4; ++dt)
                    oacc[rt][dt] = MFMA16(va[dt], pb[rt][kk], oacc[rt][dt]);
        }

        if (kt < 15) {   // write prefetched tile into the other buffer
            #pragma unroll
            for (int half = 0; half < 2; ++half) {
                const int r = srow + half * 32;
                *reinterpret_cast<uint4*>(&Ks [cur ^ 1][r * LDT + scol]) = kr[half];
                *reinterpret_cast<uint4*>(&Vts[cur ^ 1][r * LDT + scol]) = vr[half];
            }
        }
    }

    // epilogue: den reduce over quad-lanes (same q = l15), normalize, store
    #pragma unroll
    for (int rt = 0; rt < 2; ++rt) {
        float v = den[rt];
        v += __shfl_xor(v, 16);
        v += __shfl_xor(v, 32);
        const float inv = mrow[rt] ? 1.0f / v : __builtin_nanf("");
        const size_t row = (size_t)(b * N_ + q0 + rt * 16 + l15);
        #pragma unroll
        for (int dt = 0; dt < 4; ++dt) {
            ushort4 o;
            o.x = f2bf(oacc[rt][dt][0] * inv);
            o.y = f2bf(oacc[rt][dt][1] * inv);
            o.z = f2bf(oacc[rt][dt][2] * inv);
            o.w = f2bf(oacc[rt][dt][3] * inv);
            *reinterpret_cast<ushort4*>(
                &y[row * C_ + ho + dt * 16 + quad * 4]) = o;
        }
    }
}

// ---------------------------------------------------------------------------
extern "C" void kernel_launch(void* const* d_in, const int* in_sizes, int n_in,
                              void* d_out, int out_size, void* d_ws, size_t ws_size,
                              hipStream_t stream)
{
    const float* x      = (const float*)d_in[0];
    const int*   pad    = (const int*)d_in[1];
    const float* w_attn = (const float*)d_in[2];
    const float* b_attn = (const float*)d_in[3];
    const float* w_proj = (const float*)d_in[4];
    const float* b_proj = (const float*)d_in[5];
    float* out = (float*)d_out;

    // ws (bf16 elems): qk [B*N,2C] | vt [B,H,D,N] | y(=xb) [B*N,C] | wat | wpt
    ushort_t* qkb = (ushort_t*)d_ws;
    ushort_t* vtb = qkb + (size_t)B_ * N_ * C2;
    ushort_t* y   = vtb + (size_t)B_ * H_ * D_ * N_;
    ushort_t* xb  = y;   // consumed by gemm1 before attn overwrites with y
    ushort_t* wat = y + (size_t)B_ * N_ * C_;
    ushort_t* wpt = wat + (size_t)C3 * C_;

    const int M = B_ * N_;

    // 0) conversions
    cvt_bf16<<<dim3((M * C_) / (256 * 4)), dim3(256), 0, stream>>>(x, xb, M * C_);
    transpose_to_bf16<<<dim3(C3 / 32, C_ / 32), dim3(256), 0, stream>>>(
        w_attn, wat, C_, C3);
    transpose_to_bf16<<<dim3(C_ / 32, C_ / 32), dim3(256), 0, stream>>>(
        w_proj, wpt, C_, C_);

    // 1) qkv projection: Q (pre-scaled 0.125*log2e), K -> qkb; V -> vtb^T
    gemm_mfma<ushort_t, true><<<dim3(C3 / 128, M / 128), dim3(256), 0, stream>>>(
        xb, wat, b_attn, qkb, C2, vtb, M, C_, C3);

    // 2) attention -> y
    attn_mfma<<<dim3(B_ * H_ * 8), dim3(256), 0, stream>>>(qkb, vtb, pad, y);

    // 3) out = y @ w_proj + b_proj
    gemm_mfma<float, false><<<dim3(C_ / 128, M / 128), dim3(256), 0, stream>>>(
        y, wpt, b_proj, out, C_, nullptr, M, C_, C_);
}

// Round 9
// 238.012 us; speedup vs baseline: 1.0074x; 1.0074x over previous
//
#include <hip/hip_runtime.h>
#include <hip/hip_bf16.h>

// Problem constants (CausalSelfAttention_23768349016530)
#define B_  8
#define N_  1024
#define C_  768
#define H_  12
#define D_  64
#define C3  2304   // 3*C
#define C2  1536   // 2*C

typedef unsigned short ushort_t;
typedef __attribute__((ext_vector_type(8))) short bf16x8;   // 8 bf16 = 4 VGPR
typedef __attribute__((ext_vector_type(4))) short bf16x4;   // 4 bf16 = 2 VGPR
typedef __attribute__((ext_vector_type(4))) float f32x4;    // MFMA 16x16 accumulator
typedef __attribute__((ext_vector_type(2))) unsigned int uint32x2;

#if __has_builtin(__builtin_amdgcn_mfma_f32_16x16x16_bf16)
#define MFMA16(A, B, C) __builtin_amdgcn_mfma_f32_16x16x16_bf16(A, B, C, 0, 0, 0)
#else
#define MFMA16(A, B, C) __builtin_amdgcn_mfma_f32_16x16x16bf16_1k(A, B, C, 0, 0, 0)
#endif

// exp2: native v_exp_f32
__device__ __forceinline__ float fast_exp2(float x) {
#if __has_builtin(__builtin_amdgcn_exp2f)
    return __builtin_amdgcn_exp2f(x);
#else
    return exp2f(x);
#endif
}

__device__ __forceinline__ float bf2f(ushort_t u) {
    union { unsigned int i; float f; } v;
    v.i = ((unsigned int)u) << 16;
    return v.f;
}

__device__ __forceinline__ ushort_t f2bf(float f) {
    union { float f; unsigned int i; } v;
    v.f = f;
    unsigned int x = v.i;
    if ((x & 0x7f800000u) == 0x7f800000u && (x & 0x007fffffu))
        return (ushort_t)((x >> 16) | 0x0040u);   // quiet NaN
    return (ushort_t)((x + 0x7fffu + ((x >> 16) & 1u)) >> 16);  // RNE
}

__device__ __forceinline__ void st1(float* p, float v) { *p = v; }
__device__ __forceinline__ void st1(ushort_t* p, float v) { *p = f2bf(v); }

// ---------------------------------------------------------------------------
// fp32 -> bf16 elementwise (for x)
// ---------------------------------------------------------------------------
__global__ __launch_bounds__(256) void cvt_bf16(
    const float* __restrict__ X, ushort_t* __restrict__ Y, int n)
{
    int i = (blockIdx.x * 256 + threadIdx.x) * 4;
    if (i < n) {
        float4 f = *reinterpret_cast<const float4*>(X + i);
        ushort4 o;
        o.x = f2bf(f.x); o.y = f2bf(f.y); o.z = f2bf(f.z); o.w = f2bf(f.w);
        *reinterpret_cast<ushort4*>(Y + i) = o;
    }
}

// ---------------------------------------------------------------------------
// W[K][Nn] fp32  ->  WT[Nn][K] bf16   (32x32 LDS tile transpose)
// ---------------------------------------------------------------------------
__global__ __launch_bounds__(256) void transpose_to_bf16(
    const float* __restrict__ W, ushort_t* __restrict__ WT, int K, int Nn)
{
    __shared__ float t[32][33];
    const int n0 = blockIdx.x * 32, k0 = blockIdx.y * 32;
    const int tx = threadIdx.x & 31, ty = threadIdx.x >> 5;   // ty: 0..7
    #pragma unroll
    for (int i = 0; i < 4; ++i) {
        const int k = ty + i * 8;
        t[k][tx] = W[(size_t)(k0 + k) * Nn + n0 + tx];
    }
    __syncthreads();
    #pragma unroll
    for (int i = 0; i < 4; ++i) {
        const int n = ty + i * 8;
        WT[(size_t)(n0 + n) * K + k0 + tx] = f2bf(t[tx][n]);
    }
}

// ---------------------------------------------------------------------------
// MFMA GEMM: 128x128 tile, BK=64, 256 thr, XOR-swizzled LDS.
// SCALEQ: multiply (acc+bias) by 0.125*log2(e) for Q columns (< C_), folding
// both the softmax scale and the exp->exp2 conversion into Q.
// vtOut!=null && col0>=2C: write V transposed to vt[b][h][d][n].
// ---------------------------------------------------------------------------
#define GBK 64
#define QSCALE 0.18033688011112042f   // 0.125 * log2(e)

__device__ __forceinline__ void gld_lds16(const ushort_t* g, ushort_t* lds) {
    __builtin_amdgcn_global_load_lds(
        (const __attribute__((address_space(1))) void*)g,
        (__attribute__((address_space(3))) void*)lds, 16, 0, 0);
}

template<typename TO, bool SCALEQ>
__global__ __launch_bounds__(256) void gemm_mfma(
    const ushort_t* __restrict__ A, const ushort_t* __restrict__ BT,
    const float* __restrict__ bias, TO* __restrict__ Y, int ldY,
    ushort_t* __restrict__ vtOut, int M, int K, int Nn)
{
    __shared__ ushort_t As[128 * GBK];   // [row][slot^], 128B rows
    __shared__ ushort_t Bs[128 * GBK];

    const int tid  = threadIdx.x;
    const int wave = tid >> 6;
    const int lane = tid & 63;
    const int row0 = blockIdx.y * 128;
    const int col0 = blockIdx.x * 128;
    const int wr   = (wave >> 1) * 64;
    const int wc   = (wave & 1) * 64;
    const int l15  = lane & 15;
    const int quad = lane >> 4;
    const int l7   = l15 & 7;

    const int srow = lane >> 3;                 // 0..7
    const int sg   = (lane & 7) ^ srow;         // data granule to fetch

    f32x4 acc[4][4] = {};

    for (int k0 = 0; k0 < K; k0 += GBK) {
        __syncthreads();
        #pragma unroll
        for (int it = 0; it < 4; ++it) {
            const int baseRow = wave * 32 + it * 8;           // wave-uniform
            const int r = baseRow + srow;
            gld_lds16(&A [(size_t)(row0 + r) * K + k0 + sg * 8], &As[baseRow * GBK]);
            gld_lds16(&BT[(size_t)(col0 + r) * K + k0 + sg * 8], &Bs[baseRow * GBK]);
        }
        __syncthreads();

        #pragma unroll
        for (int kc = 0; kc < 2; ++kc) {
            bf16x8 af[4], bf[4];
            #pragma unroll
            for (int i = 0; i < 4; ++i) {
                const int aslot = (kc * 4 + quad) ^ l7;
                af[i] = *reinterpret_cast<const bf16x8*>(
                    &As[(wr + i * 16 + l15) * GBK + aslot * 8]);
                bf[i] = *reinterpret_cast<const bf16x8*>(
                    &Bs[(wc + i * 16 + l15) * GBK + aslot * 8]);
            }
            #pragma unroll
            for (int i = 0; i < 4; ++i)
                #pragma unroll
                for (int j = 0; j < 4; ++j)
                    acc[i][j] = __builtin_amdgcn_mfma_f32_16x16x32_bf16(
                        af[i], bf[j], acc[i][j], 0, 0, 0);
        }
    }

    const float qs = (SCALEQ && (col0 + wc) < C_) ? QSCALE : 1.0f;

    if (vtOut != nullptr && col0 >= C2) {
        // V part: write transposed vt[b][h][d][token]
        #pragma unroll
        for (int i = 0; i < 4; ++i) {
            const int r0 = row0 + wr + i * 16 + quad * 4;   // token base
            const int bb = r0 >> 10;
            const int n  = r0 & 1023;
            #pragma unroll
            for (int j = 0; j < 4; ++j) {
                const int c  = col0 + wc + j * 16 + l15;
                const int cv = c - C2;
                const int hh = cv >> 6, d = cv & 63;
                const float bv = bias[c];
                ushort4 o;
                o.x = f2bf(acc[i][j][0] + bv);
                o.y = f2bf(acc[i][j][1] + bv);
                o.z = f2bf(acc[i][j][2] + bv);
                o.w = f2bf(acc[i][j][3] + bv);
                *reinterpret_cast<ushort4*>(
                    &vtOut[((size_t)(bb * H_ + hh) * D_ + d) * N_ + n]) = o;
            }
        }
    } else {
        #pragma unroll
        for (int i = 0; i < 4; ++i) {
            const int r = row0 + wr + i * 16 + quad * 4;
            #pragma unroll
            for (int j = 0; j < 4; ++j) {
                const int c = col0 + wc + j * 16 + l15;
                const float bv = bias[c];
                #pragma unroll
                for (int t = 0; t < 4; ++t)
                    st1(&Y[(size_t)(r + t) * ldY + c], (acc[i][j][t] + bv) * qs);
            }
        }
    }
}

// ---------------------------------------------------------------------------
// MFMA attention, S^T formulation (round 8) with the scratch-spill fixed:
// the P bf16 pack is now a register-level __builtin_bit_cast (uint32x2 ->
// bf16x4) instead of a union containing an array, which forced an alloca
// and ~150 MB/dispatch of scratch writebacks (round-8 WRITE_SIZE counter).
// ---------------------------------------------------------------------------
#define LDT 72

__global__ __launch_bounds__(256) void attn_mfma(
    const ushort_t* __restrict__ qk, const ushort_t* __restrict__ vt,
    const int* __restrict__ pad_mask, ushort_t* __restrict__ y)
{
    __shared__ ushort_t Ks [2][64 * LDT];   // K tile  [key][d]
    __shared__ ushort_t Vts[2][64 * LDT];   // V^T tile [d][key]

    const int tid  = threadIdx.x;
    const int wave = tid >> 6;
    const int lane = tid & 63;
    const int l15  = lane & 15;
    const int quad = lane >> 4;

    const int qt = blockIdx.x & 7;                // 8 q-tiles of 128
    const int h  = (blockIdx.x >> 3) % H_;
    const int b  = blockIdx.x / (8 * H_);
    const int q0 = qt * 128 + wave * 32;          // wave's first query row

    const ushort_t* qkB = qk + (size_t)b * N_ * C2;
    const ushort_t* vtB = vt + ((size_t)(b * H_ + h)) * D_ * N_;
    const int ho = h * D_;

    // Q as B-operand fragments: [n=q=l15][k=d=kc*32+quad*8+j]
    bf16x8 qf[2][2];
    #pragma unroll
    for (int rt = 0; rt < 2; ++rt)
        #pragma unroll
        for (int kc = 0; kc < 2; ++kc)
            qf[rt][kc] = *reinterpret_cast<const bf16x8*>(
                &qkB[(size_t)(q0 + rt * 16 + l15) * C2 + ho + kc * 32 + quad * 8]);

    // pad mask per q = rt*16 + l15 (epilogue only)
    int mrow[2];
    #pragma unroll
    for (int rt = 0; rt < 2; ++rt)
        mrow[rt] = pad_mask[b * N_ + q0 + rt * 16 + l15];

    f32x4 oacc[2][4] = {};   // [rt(q)][dt(d)] ; O^T: d=quad*4+t, q=l15
    float den[2] = {};

    const int srow = tid >> 3;          // staging: 0..31
    const int scol = (tid & 7) * 8;     // 16B granule within 64-elem row

    uint4 kr[2], vr[2];
    // prologue: tile 0 -> regs -> buf 0
    #pragma unroll
    for (int half = 0; half < 2; ++half) {
        const int r = srow + half * 32;
        kr[half] = *reinterpret_cast<const uint4*>(&qkB[(size_t)r * C2 + C_ + ho + scol]);
        vr[half] = *reinterpret_cast<const uint4*>(&vtB[(size_t)r * N_ + scol]);
    }
    #pragma unroll
    for (int half = 0; half < 2; ++half) {
        const int r = srow + half * 32;
        *reinterpret_cast<uint4*>(&Ks [0][r * LDT + scol]) = kr[half];
        *reinterpret_cast<uint4*>(&Vts[0][r * LDT + scol]) = vr[half];
    }

    for (int kt = 0; kt < 16; ++kt) {
        const int cur = kt & 1;
        if (kt < 15) {   // prefetch next tile into registers (latency hidden)
            const int k0 = (kt + 1) * 64;
            #pragma unroll
            for (int half = 0; half < 2; ++half) {
                const int r = srow + half * 32;
                kr[half] = *reinterpret_cast<const uint4*>(
                    &qkB[(size_t)(k0 + r) * C2 + C_ + ho + scol]);
                vr[half] = *reinterpret_cast<const uint4*>(
                    &vtB[(size_t)r * N_ + k0 + scol]);
            }
        }
        __syncthreads();   // buf[cur] writes visible; prev compute done

        // S^T = K Q^T : A=kf (m=key), B=qf (n=q)
        f32x4 s[2][4] = {};   // [rt(q)][ct(key tile)]
        #pragma unroll
        for (int kc = 0; kc < 2; ++kc) {
            bf16x8 kf[4];
            #pragma unroll
            for (int ct = 0; ct < 4; ++ct)
                kf[ct] = *reinterpret_cast<const bf16x8*>(
                    &Ks[cur][(ct * 16 + l15) * LDT + kc * 32 + quad * 8]);
            #pragma unroll
            for (int rt = 0; rt < 2; ++rt)
                #pragma unroll
                for (int ct = 0; ct < 4; ++ct)
                    s[rt][ct] = __builtin_amdgcn_mfma_f32_16x16x32_bf16(
                        kf[ct], qf[rt][kc], s[rt][ct], 0, 0, 0);
        }

        // p = exp2(s); den += p; pack pairs to bf16 (pure register bitcast)
        bf16x4 pb[2][4];
        #pragma unroll
        for (int rt = 0; rt < 2; ++rt)
            #pragma unroll
            for (int ct = 0; ct < 4; ++ct) {
                float p0 = fast_exp2(s[rt][ct][0]);
                float p1 = fast_exp2(s[rt][ct][1]);
                float p2 = fast_exp2(s[rt][ct][2]);
                float p3 = fast_exp2(s[rt][ct][3]);
                den[rt] += (p0 + p1) + (p2 + p3);
                uint32x2 pk;
                pk.x = ((__float_as_uint(p0) + 0x8000u) >> 16)
                     | ((__float_as_uint(p1) + 0x8000u) & 0xffff0000u);
                pk.y = ((__float_as_uint(p2) + 0x8000u) >> 16)
                     | ((__float_as_uint(p3) + 0x8000u) & 0xffff0000u);
                pb[rt][ct] = __builtin_bit_cast(bf16x4, pk);
            }

        // O^T += V^T P : A = V^T frag [m=d=l15][k=key=quad*4+i], B = pb
        #pragma unroll
        for (int kk = 0; kk < 4; ++kk) {
            bf16x4 va[4];
            #pragma unroll
            for (int dt = 0; dt < 4; ++dt)
                va[dt] = *reinterpret_cast<const bf16x4*>(
                    &Vts[cur][(dt * 16 + l15) * LDT + kk * 16 + quad * 4]);
            #pragma unroll
            for (int rt = 0; rt < 2; ++rt)
                #pragma unroll
                for (int dt = 0; dt < 4; ++dt)
                    oacc[rt][dt] = MFMA16(va[dt], pb[rt][kk], oacc[rt][dt]);
        }

        if (kt < 15) {   // write prefetched tile into the other buffer
            #pragma unroll
            for (int half = 0; half < 2; ++half) {
                const int r = srow + half * 32;
                *reinterpret_cast<uint4*>(&Ks [cur ^ 1][r * LDT + scol]) = kr[half];
                *reinterpret_cast<uint4*>(&Vts[cur ^ 1][r * LDT + scol]) = vr[half];
            }
        }
    }

    // epilogue: den reduce over quad-lanes (same q = l15), normalize, store
    #pragma unroll
    for (int rt = 0; rt < 2; ++rt) {
        float v = den[rt];
        v += __shfl_xor(v, 16);
        v += __shfl_xor(v, 32);
        const float inv = mrow[rt] ? 1.0f / v : __builtin_nanf("");
        const size_t row = (size_t)(b * N_ + q0 + rt * 16 + l15);
        #pragma unroll
        for (int dt = 0; dt < 4; ++dt) {
            ushort4 o;
            o.x = f2bf(oacc[rt][dt][0] * inv);
            o.y = f2bf(oacc[rt][dt][1] * inv);
            o.z = f2bf(oacc[rt][dt][2] * inv);
            o.w = f2bf(oacc[rt][dt][3] * inv);
            *reinterpret_cast<ushort4*>(
                &y[row * C_ + ho + dt * 16 + quad * 4]) = o;
        }
    }
}

// ---------------------------------------------------------------------------
extern "C" void kernel_launch(void* const* d_in, const int* in_sizes, int n_in,
                              void* d_out, int out_size, void* d_ws, size_t ws_size,
                              hipStream_t stream)
{
    const float* x      = (const float*)d_in[0];
    const int*   pad    = (const int*)d_in[1];
    const float* w_attn = (const float*)d_in[2];
    const float* b_attn = (const float*)d_in[3];
    const float* w_proj = (const float*)d_in[4];
    const float* b_proj = (const float*)d_in[5];
    float* out = (float*)d_out;

    // ws (bf16 elems): qk [B*N,2C] | vt [B,H,D,N] | y(=xb) [B*N,C] | wat | wpt
    ushort_t* qkb = (ushort_t*)d_ws;
    ushort_t* vtb = qkb + (size_t)B_ * N_ * C2;
    ushort_t* y   = vtb + (size_t)B_ * H_ * D_ * N_;
    ushort_t* xb  = y;   // consumed by gemm1 before attn overwrites with y
    ushort_t* wat = y + (size_t)B_ * N_ * C_;
    ushort_t* wpt = wat + (size_t)C3 * C_;

    const int M = B_ * N_;

    // 0) conversions
    cvt_bf16<<<dim3((M * C_) / (256 * 4)), dim3(256), 0, stream>>>(x, xb, M * C_);
    transpose_to_bf16<<<dim3(C3 / 32, C_ / 32), dim3(256), 0, stream>>>(
        w_attn, wat, C_, C3);
    transpose_to_bf16<<<dim3(C_ / 32, C_ / 32), dim3(256), 0, stream>>>(
        w_proj, wpt, C_, C_);

    // 1) qkv projection: Q (pre-scaled 0.125*log2e), K -> qkb; V -> vtb^T
    gemm_mfma<ushort_t, true><<<dim3(C3 / 128, M / 128), dim3(256), 0, stream>>>(
        xb, wat, b_attn, qkb, C2, vtb, M, C_, C3);

    // 2) attention -> y
    attn_mfma<<<dim3(B_ * H_ * 8), dim3(256), 0, stream>>>(qkb, vtb, pad, y);

    // 3) out = y @ w_proj + b_proj
    gemm_mfma<float, false><<<dim3(C_ / 128, M / 128), dim3(256), 0, stream>>>(
        y, wpt, b_proj, out, C_, nullptr, M, C_, C_);
}

// Round 10
// 219.276 us; speedup vs baseline: 1.0934x; 1.0854x over previous
//
#include <hip/hip_runtime.h>
#include <hip/hip_bf16.h>

// Problem constants (CausalSelfAttention_23768349016530)
#define B_  8
#define N_  1024
#define C_  768
#define H_  12
#define D_  64
#define C3  2304   // 3*C
#define C2  1536   // 2*C

typedef unsigned short ushort_t;
typedef __attribute__((ext_vector_type(8))) short bf16x8;   // 8 bf16 = 4 VGPR
typedef __attribute__((ext_vector_type(4))) short bf16x4;   // 4 bf16 = 2 VGPR
typedef __attribute__((ext_vector_type(4))) float f32x4;    // MFMA 16x16 accumulator
typedef __attribute__((ext_vector_type(2))) unsigned int uint32x2;

#if __has_builtin(__builtin_amdgcn_mfma_f32_16x16x16_bf16)
#define MFMA16(A, B, C) __builtin_amdgcn_mfma_f32_16x16x16_bf16(A, B, C, 0, 0, 0)
#else
#define MFMA16(A, B, C) __builtin_amdgcn_mfma_f32_16x16x16bf16_1k(A, B, C, 0, 0, 0)
#endif

// exp2: native v_exp_f32
__device__ __forceinline__ float fast_exp2(float x) {
#if __has_builtin(__builtin_amdgcn_exp2f)
    return __builtin_amdgcn_exp2f(x);
#else
    return exp2f(x);
#endif
}

__device__ __forceinline__ float bf2f(ushort_t u) {
    union { unsigned int i; float f; } v;
    v.i = ((unsigned int)u) << 16;
    return v.f;
}

__device__ __forceinline__ ushort_t f2bf(float f) {
    union { float f; unsigned int i; } v;
    v.f = f;
    unsigned int x = v.i;
    if ((x & 0x7f800000u) == 0x7f800000u && (x & 0x007fffffu))
        return (ushort_t)((x >> 16) | 0x0040u);   // quiet NaN
    return (ushort_t)((x + 0x7fffu + ((x >> 16) & 1u)) >> 16);  // RNE
}

__device__ __forceinline__ void st1(float* p, float v) { *p = v; }
__device__ __forceinline__ void st1(ushort_t* p, float v) { *p = f2bf(v); }

// ---------------------------------------------------------------------------
// fp32 -> bf16 elementwise (for x)
// ---------------------------------------------------------------------------
__global__ __launch_bounds__(256) void cvt_bf16(
    const float* __restrict__ X, ushort_t* __restrict__ Y, int n)
{
    int i = (blockIdx.x * 256 + threadIdx.x) * 4;
    if (i < n) {
        float4 f = *reinterpret_cast<const float4*>(X + i);
        ushort4 o;
        o.x = f2bf(f.x); o.y = f2bf(f.y); o.z = f2bf(f.z); o.w = f2bf(f.w);
        *reinterpret_cast<ushort4*>(Y + i) = o;
    }
}

// ---------------------------------------------------------------------------
// W[K][Nn] fp32  ->  WT[Nn][K] bf16   (32x32 LDS tile transpose)
// ---------------------------------------------------------------------------
__global__ __launch_bounds__(256) void transpose_to_bf16(
    const float* __restrict__ W, ushort_t* __restrict__ WT, int K, int Nn)
{
    __shared__ float t[32][33];
    const int n0 = blockIdx.x * 32, k0 = blockIdx.y * 32;
    const int tx = threadIdx.x & 31, ty = threadIdx.x >> 5;   // ty: 0..7
    #pragma unroll
    for (int i = 0; i < 4; ++i) {
        const int k = ty + i * 8;
        t[k][tx] = W[(size_t)(k0 + k) * Nn + n0 + tx];
    }
    __syncthreads();
    #pragma unroll
    for (int i = 0; i < 4; ++i) {
        const int n = ty + i * 8;
        WT[(size_t)(n0 + n) * K + k0 + tx] = f2bf(t[tx][n]);
    }
}

// ---------------------------------------------------------------------------
// MFMA GEMM: 128x128 tile, BK=64, 256 thr, XOR-swizzled LDS.
// SCALEQ: multiply (acc+bias) by 0.125*log2(e) for Q columns (< C_), folding
// both the softmax scale and the exp->exp2 conversion into Q.
// vtOut!=null && col0>=2C: write V transposed to vt[b][h][d][n].
// ---------------------------------------------------------------------------
#define GBK 64
#define QSCALE 0.18033688011112042f   // 0.125 * log2(e)

__device__ __forceinline__ void gld_lds16(const ushort_t* g, ushort_t* lds) {
    __builtin_amdgcn_global_load_lds(
        (const __attribute__((address_space(1))) void*)g,
        (__attribute__((address_space(3))) void*)lds, 16, 0, 0);
}

template<typename TO, bool SCALEQ>
__global__ __launch_bounds__(256) void gemm_mfma(
    const ushort_t* __restrict__ A, const ushort_t* __restrict__ BT,
    const float* __restrict__ bias, TO* __restrict__ Y, int ldY,
    ushort_t* __restrict__ vtOut, int M, int K, int Nn)
{
    __shared__ ushort_t As[128 * GBK];   // [row][slot^], 128B rows
    __shared__ ushort_t Bs[128 * GBK];

    const int tid  = threadIdx.x;
    const int wave = tid >> 6;
    const int lane = tid & 63;
    const int row0 = blockIdx.y * 128;
    const int col0 = blockIdx.x * 128;
    const int wr   = (wave >> 1) * 64;
    const int wc   = (wave & 1) * 64;
    const int l15  = lane & 15;
    const int quad = lane >> 4;
    const int l7   = l15 & 7;

    const int srow = lane >> 3;                 // 0..7
    const int sg   = (lane & 7) ^ srow;         // data granule to fetch

    f32x4 acc[4][4] = {};

    for (int k0 = 0; k0 < K; k0 += GBK) {
        __syncthreads();
        #pragma unroll
        for (int it = 0; it < 4; ++it) {
            const int baseRow = wave * 32 + it * 8;           // wave-uniform
            const int r = baseRow + srow;
            gld_lds16(&A [(size_t)(row0 + r) * K + k0 + sg * 8], &As[baseRow * GBK]);
            gld_lds16(&BT[(size_t)(col0 + r) * K + k0 + sg * 8], &Bs[baseRow * GBK]);
        }
        __syncthreads();

        #pragma unroll
        for (int kc = 0; kc < 2; ++kc) {
            bf16x8 af[4], bf[4];
            #pragma unroll
            for (int i = 0; i < 4; ++i) {
                const int aslot = (kc * 4 + quad) ^ l7;
                af[i] = *reinterpret_cast<const bf16x8*>(
                    &As[(wr + i * 16 + l15) * GBK + aslot * 8]);
                bf[i] = *reinterpret_cast<const bf16x8*>(
                    &Bs[(wc + i * 16 + l15) * GBK + aslot * 8]);
            }
            #pragma unroll
            for (int i = 0; i < 4; ++i)
                #pragma unroll
                for (int j = 0; j < 4; ++j)
                    acc[i][j] = __builtin_amdgcn_mfma_f32_16x16x32_bf16(
                        af[i], bf[j], acc[i][j], 0, 0, 0);
        }
    }

    const float qs = (SCALEQ && (col0 + wc) < C_) ? QSCALE : 1.0f;

    if (vtOut != nullptr && col0 >= C2) {
        // V part: write transposed vt[b][h][d][token]
        #pragma unroll
        for (int i = 0; i < 4; ++i) {
            const int r0 = row0 + wr + i * 16 + quad * 4;   // token base
            const int bb = r0 >> 10;
            const int n  = r0 & 1023;
            #pragma unroll
            for (int j = 0; j < 4; ++j) {
                const int c  = col0 + wc + j * 16 + l15;
                const int cv = c - C2;
                const int hh = cv >> 6, d = cv & 63;
                const float bv = bias[c];
                ushort4 o;
                o.x = f2bf(acc[i][j][0] + bv);
                o.y = f2bf(acc[i][j][1] + bv);
                o.z = f2bf(acc[i][j][2] + bv);
                o.w = f2bf(acc[i][j][3] + bv);
                *reinterpret_cast<ushort4*>(
                    &vtOut[((size_t)(bb * H_ + hh) * D_ + d) * N_ + n]) = o;
            }
        }
    } else {
        #pragma unroll
        for (int i = 0; i < 4; ++i) {
            const int r = row0 + wr + i * 16 + quad * 4;
            #pragma unroll
            for (int j = 0; j < 4; ++j) {
                const int c = col0 + wc + j * 16 + l15;
                const float bv = bias[c];
                #pragma unroll
                for (int t = 0; t < 4; ++t)
                    st1(&Y[(size_t)(r + t) * ldY + c], (acc[i][j][t] + bv) * qs);
            }
        }
    }
}

// ---------------------------------------------------------------------------
// MFMA attention, S^T formulation. Peak live-VGPR count of this structure is
// ~110 (qf 16 + oacc 16 + kr/vr 16 + s 32 + pb 16 + transients). Without a
// hint the allocator caps at 80 and SPILLS per K-tile (~150 MB/dispatch of
// scratch writebacks observed in rounds 8/9). Grid = 768 blocks = 3/CU, so
// occupancy >3 blocks/CU is unreachable: __launch_bounds__(256,3) raises the
// VGPR budget to ~170/wave at zero occupancy cost -> no spill.
// ---------------------------------------------------------------------------
#define LDT 72

__global__ __launch_bounds__(256, 3) void attn_mfma(
    const ushort_t* __restrict__ qk, const ushort_t* __restrict__ vt,
    const int* __restrict__ pad_mask, ushort_t* __restrict__ y)
{
    __shared__ ushort_t Ks [2][64 * LDT];   // K tile  [key][d]
    __shared__ ushort_t Vts[2][64 * LDT];   // V^T tile [d][key]

    const int tid  = threadIdx.x;
    const int wave = tid >> 6;
    const int lane = tid & 63;
    const int l15  = lane & 15;
    const int quad = lane >> 4;

    const int qt = blockIdx.x & 7;                // 8 q-tiles of 128
    const int h  = (blockIdx.x >> 3) % H_;
    const int b  = blockIdx.x / (8 * H_);
    const int q0 = qt * 128 + wave * 32;          // wave's first query row

    const ushort_t* qkB = qk + (size_t)b * N_ * C2;
    const ushort_t* vtB = vt + ((size_t)(b * H_ + h)) * D_ * N_;
    const int ho = h * D_;

    // Q as B-operand fragments: [n=q=l15][k=d=kc*32+quad*8+j]
    bf16x8 qf[2][2];
    #pragma unroll
    for (int rt = 0; rt < 2; ++rt)
        #pragma unroll
        for (int kc = 0; kc < 2; ++kc)
            qf[rt][kc] = *reinterpret_cast<const bf16x8*>(
                &qkB[(size_t)(q0 + rt * 16 + l15) * C2 + ho + kc * 32 + quad * 8]);

    // pad mask per q = rt*16 + l15 (epilogue only)
    int mrow[2];
    #pragma unroll
    for (int rt = 0; rt < 2; ++rt)
        mrow[rt] = pad_mask[b * N_ + q0 + rt * 16 + l15];

    f32x4 oacc[2][4] = {};   // [rt(q)][dt(d)] ; O^T: d=quad*4+t, q=l15
    float den[2] = {};

    const int srow = tid >> 3;          // staging: 0..31
    const int scol = (tid & 7) * 8;     // 16B granule within 64-elem row

    uint4 kr[2], vr[2];
    // prologue: tile 0 -> regs -> buf 0
    #pragma unroll
    for (int half = 0; half < 2; ++half) {
        const int r = srow + half * 32;
        kr[half] = *reinterpret_cast<const uint4*>(&qkB[(size_t)r * C2 + C_ + ho + scol]);
        vr[half] = *reinterpret_cast<const uint4*>(&vtB[(size_t)r * N_ + scol]);
    }
    #pragma unroll
    for (int half = 0; half < 2; ++half) {
        const int r = srow + half * 32;
        *reinterpret_cast<uint4*>(&Ks [0][r * LDT + scol]) = kr[half];
        *reinterpret_cast<uint4*>(&Vts[0][r * LDT + scol]) = vr[half];
    }

    for (int kt = 0; kt < 16; ++kt) {
        const int cur = kt & 1;
        if (kt < 15) {   // prefetch next tile into registers (latency hidden)
            const int k0 = (kt + 1) * 64;
            #pragma unroll
            for (int half = 0; half < 2; ++half) {
                const int r = srow + half * 32;
                kr[half] = *reinterpret_cast<const uint4*>(
                    &qkB[(size_t)(k0 + r) * C2 + C_ + ho + scol]);
                vr[half] = *reinterpret_cast<const uint4*>(
                    &vtB[(size_t)r * N_ + k0 + scol]);
            }
        }
        __syncthreads();   // buf[cur] writes visible; prev compute done

        // S^T = K Q^T : A=kf (m=key), B=qf (n=q)
        f32x4 s[2][4] = {};   // [rt(q)][ct(key tile)]
        #pragma unroll
        for (int kc = 0; kc < 2; ++kc) {
            bf16x8 kf[4];
            #pragma unroll
            for (int ct = 0; ct < 4; ++ct)
                kf[ct] = *reinterpret_cast<const bf16x8*>(
                    &Ks[cur][(ct * 16 + l15) * LDT + kc * 32 + quad * 8]);
            #pragma unroll
            for (int rt = 0; rt < 2; ++rt)
                #pragma unroll
                for (int ct = 0; ct < 4; ++ct)
                    s[rt][ct] = __builtin_amdgcn_mfma_f32_16x16x32_bf16(
                        kf[ct], qf[rt][kc], s[rt][ct], 0, 0, 0);
        }

        // p = exp2(s); den += p; pack pairs to bf16 (pure register bitcast)
        bf16x4 pb[2][4];
        #pragma unroll
        for (int rt = 0; rt < 2; ++rt)
            #pragma unroll
            for (int ct = 0; ct < 4; ++ct) {
                float p0 = fast_exp2(s[rt][ct][0]);
                float p1 = fast_exp2(s[rt][ct][1]);
                float p2 = fast_exp2(s[rt][ct][2]);
                float p3 = fast_exp2(s[rt][ct][3]);
                den[rt] += (p0 + p1) + (p2 + p3);
                uint32x2 pk;
                pk.x = ((__float_as_uint(p0) + 0x8000u) >> 16)
                     | ((__float_as_uint(p1) + 0x8000u) & 0xffff0000u);
                pk.y = ((__float_as_uint(p2) + 0x8000u) >> 16)
                     | ((__float_as_uint(p3) + 0x8000u) & 0xffff0000u);
                pb[rt][ct] = __builtin_bit_cast(bf16x4, pk);
            }

        // O^T += V^T P : A = V^T frag [m=d=l15][k=key=quad*4+i], B = pb
        #pragma unroll
        for (int kk = 0; kk < 4; ++kk) {
            bf16x4 va[4];
            #pragma unroll
            for (int dt = 0; dt < 4; ++dt)
                va[dt] = *reinterpret_cast<const bf16x4*>(
                    &Vts[cur][(dt * 16 + l15) * LDT + kk * 16 + quad * 4]);
            #pragma unroll
            for (int rt = 0; rt < 2; ++rt)
                #pragma unroll
                for (int dt = 0; dt < 4; ++dt)
                    oacc[rt][dt] = MFMA16(va[dt], pb[rt][kk], oacc[rt][dt]);
        }

        if (kt < 15) {   // write prefetched tile into the other buffer
            #pragma unroll
            for (int half = 0; half < 2; ++half) {
                const int r = srow + half * 32;
                *reinterpret_cast<uint4*>(&Ks [cur ^ 1][r * LDT + scol]) = kr[half];
                *reinterpret_cast<uint4*>(&Vts[cur ^ 1][r * LDT + scol]) = vr[half];
            }
        }
    }

    // epilogue: den reduce over quad-lanes (same q = l15), normalize, store
    #pragma unroll
    for (int rt = 0; rt < 2; ++rt) {
        float v = den[rt];
        v += __shfl_xor(v, 16);
        v += __shfl_xor(v, 32);
        const float inv = mrow[rt] ? 1.0f / v : __builtin_nanf("");
        const size_t row = (size_t)(b * N_ + q0 + rt * 16 + l15);
        #pragma unroll
        for (int dt = 0; dt < 4; ++dt) {
            ushort4 o;
            o.x = f2bf(oacc[rt][dt][0] * inv);
            o.y = f2bf(oacc[rt][dt][1] * inv);
            o.z = f2bf(oacc[rt][dt][2] * inv);
            o.w = f2bf(oacc[rt][dt][3] * inv);
            *reinterpret_cast<ushort4*>(
                &y[row * C_ + ho + dt * 16 + quad * 4]) = o;
        }
    }
}

// ---------------------------------------------------------------------------
extern "C" void kernel_launch(void* const* d_in, const int* in_sizes, int n_in,
                              void* d_out, int out_size, void* d_ws, size_t ws_size,
                              hipStream_t stream)
{
    const float* x      = (const float*)d_in[0];
    const int*   pad    = (const int*)d_in[1];
    const float* w_attn = (const float*)d_in[2];
    const float* b_attn = (const float*)d_in[3];
    const float* w_proj = (const float*)d_in[4];
    const float* b_proj = (const float*)d_in[5];
    float* out = (float*)d_out;

    // ws (bf16 elems): qk [B*N,2C] | vt [B,H,D,N] | y(=xb) [B*N,C] | wat | wpt
    ushort_t* qkb = (ushort_t*)d_ws;
    ushort_t* vtb = qkb + (size_t)B_ * N_ * C2;
    ushort_t* y   = vtb + (size_t)B_ * H_ * D_ * N_;
    ushort_t* xb  = y;   // consumed by gemm1 before attn overwrites with y
    ushort_t* wat = y + (size_t)B_ * N_ * C_;
    ushort_t* wpt = wat + (size_t)C3 * C_;

    const int M = B_ * N_;

    // 0) conversions
    cvt_bf16<<<dim3((M * C_) / (256 * 4)), dim3(256), 0, stream>>>(x, xb, M * C_);
    transpose_to_bf16<<<dim3(C3 / 32, C_ / 32), dim3(256), 0, stream>>>(
        w_attn, wat, C_, C3);
    transpose_to_bf16<<<dim3(C_ / 32, C_ / 32), dim3(256), 0, stream>>>(
        w_proj, wpt, C_, C_);

    // 1) qkv projection: Q (pre-scaled 0.125*log2e), K -> qkb; V -> vtb^T
    gemm_mfma<ushort_t, true><<<dim3(C3 / 128, M / 128), dim3(256), 0, stream>>>(
        xb, wat, b_attn, qkb, C2, vtb, M, C_, C3);

    // 2) attention -> y
    attn_mfma<<<dim3(B_ * H_ * 8), dim3(256), 0, stream>>>(qkb, vtb, pad, y);

    // 3) out = y @ w_proj + b_proj
    gemm_mfma<float, false><<<dim3(C_ / 128, M / 128), dim3(256), 0, stream>>>(
        y, wpt, b_proj, out, C_, nullptr, M, C_, C_);
}